// Round 1
// baseline (169.004 us; speedup 1.0000x reference)
//
#include <hip/hip_runtime.h>

typedef unsigned short u16;
typedef unsigned int u32;
typedef __attribute__((ext_vector_type(8))) short short8;    // 8 bf16 (4 VGPRs)
typedef __attribute__((ext_vector_type(4))) float floatx4;   // 4 fp32 acc
typedef __attribute__((ext_vector_type(4))) u32 uint4v;

// Pack two fp32 -> two bf16 (RNE) in one dword: low16=bf(a), high16=bf(b).
__device__ __forceinline__ u32 pack2bf(float a, float b) {
    u32 ua = __float_as_uint(a), ub = __float_as_uint(b);
    ua += 0x7fffu + ((ua >> 16) & 1u);   // RNE
    ub += 0x7fffu + ((ub >> 16) & 1u);
    // bytes: [ub31:24 | ub23:16 | ua31:24 | ua23:16]
    return __builtin_amdgcn_perm(ub, ua, 0x07060302);
}

// ---------------------------------------------------------------------------
// Kernel N: L2-normalize each 128x64 tile ONCE (200 tiles total: 100 q + 100 s),
// pack to bf16, store to workspace in MFMA-FRAGMENT ORDER:
//   tile byte addr(rowblk, ks, lane) = tile*16384 + (rowblk*2 + ks)*1024 + lane*16
// where lane = quad*16 + l15, holding elems [ks*32 + quad*8 .. +8) of
// row (rowblk*16 + l15). This makes each GEMM fragment load one fully
// coalesced global_load_dwordx4 (1 KB per wave-instruction).
// ---------------------------------------------------------------------------
__global__ __launch_bounds__(256)
void normalize_pack_kernel(const float* __restrict__ q,
                           const float* __restrict__ s,
                           u16* __restrict__ ws)
{
    const int t      = threadIdx.x;
    const int blk    = blockIdx.x;        // 0..199
    const int tensor = blk / 100;         // 0 = q, 1 = s
    const int tile   = blk % 100;         // b*25 + i  (or j)

    const float* src = (tensor ? s : q) + (size_t)tile * 8192;   // 128x64 fp32
    u16*         dst = ws + (size_t)blk * 8192;                  // 16 KB bf16 tile

    // thread t: row = t>>1, half = t&1 (32 floats). Pair (t, t^1) shares a row.
    const int row  = t >> 1;
    const int half = t & 1;               // == ks
    const float* gp = src + row * 64 + half * 32;

    float4 f[8];
#pragma unroll
    for (int c = 0; c < 8; ++c) f[c] = ((const float4*)gp)[c];
    float ss = 0.f;
#pragma unroll
    for (int c = 0; c < 8; ++c)
        ss += f[c].x*f[c].x + f[c].y*f[c].y + f[c].z*f[c].z + f[c].w*f[c].w;
    ss += __shfl_xor(ss, 1);                          // full-row sum of squares
    const float r = 1.0f / fmaxf(sqrtf(ss), 1e-12f);  // torch F.normalize eps

    // chunk c (==quad) covers elems [half*32 + c*8 .. +8) of this row.
    // fragment-order slot: (rowblk = row>>4, ks = half, lane = c*16 + (row&15))
    u16* base = dst + ((size_t)((row >> 4) * 2 + half) * 512) + (row & 15) * 8;
#pragma unroll
    for (int c = 0; c < 4; ++c) {
        uint4v pk;
        pk.x = pack2bf(f[2*c].x * r,   f[2*c].y * r);
        pk.y = pack2bf(f[2*c].z * r,   f[2*c].w * r);
        pk.z = pack2bf(f[2*c+1].x * r, f[2*c+1].y * r);
        pk.w = pack2bf(f[2*c+1].z * r, f[2*c+1].w * r);
        *(uint4v*)(base + c * 128) = pk;   // c*256 B = c*128 u16 (lane stride 16B)
    }
}

// ---------------------------------------------------------------------------
// Kernel G: pure MFMA + store. No LDS, no barriers, no VALU normalize.
// Each wave computes a 64x64 sub-tile of the 128x128 output.
// Fragment loads hit L2 (workspace = 3.2 MB total) as coalesced dwordx4.
// ---------------------------------------------------------------------------
__global__ __launch_bounds__(256, 4)
void cosine_gemm_kernel(const u16* __restrict__ ws,
                        float* __restrict__ out)
{
    const int t   = threadIdx.x;
    const int blk = blockIdx.x;           // == (b*25 + i)*25 + j
    const int b   = blk / 625;
    const int rem = blk % 625;
    const int i   = rem / 25;
    const int j   = rem % 25;

    const u16* qtile = ws + (size_t)(b * 25 + i) * 8192;
    const u16* stile = ws + (size_t)(100 + b * 25 + j) * 8192;

    const int wave = t >> 6;
    const int lane = t & 63;
    const int quad = lane >> 4;
    const int l15  = lane & 15;
    const int m0   = (wave >> 1) * 64;
    const int n0   = (wave & 1) * 64;

    floatx4 acc[4][4] = {};
#pragma unroll
    for (int ks = 0; ks < 2; ++ks) {
        short8 af[4], bfr[4];
#pragma unroll
        for (int mt = 0; mt < 4; ++mt)
            af[mt] = *(const short8*)(qtile +
                      (size_t)(((m0 >> 4) + mt) * 2 + ks) * 512 + lane * 8);
#pragma unroll
        for (int nt = 0; nt < 4; ++nt)
            bfr[nt] = *(const short8*)(stile +
                      (size_t)(((n0 >> 4) + nt) * 2 + ks) * 512 + lane * 8);
#pragma unroll
        for (int mt = 0; mt < 4; ++mt)
#pragma unroll
            for (int nt = 0; nt < 4; ++nt)
                acc[mt][nt] = __builtin_amdgcn_mfma_f32_16x16x32_bf16(
                    af[mt], bfr[nt], acc[mt][nt], 0, 0, 0);
    }

    // ---- Epilogue: inputs pre-normalized, so acc IS the cosine. Bare stores.
    // C/D layout (probe-verified): row = quad*4 + r, col = lane&15.
    float* obase = out + (size_t)blk * 16384 + n0 + l15;
#pragma unroll
    for (int mt = 0; mt < 4; ++mt) {
#pragma unroll
        for (int r = 0; r < 4; ++r) {
            float* op = obase + (size_t)(m0 + mt * 16 + quad * 4 + r) * 128;
#pragma unroll
            for (int nt = 0; nt < 4; ++nt)
                op[nt * 16] = acc[mt][nt][r];
        }
    }
}

// ---------------------------------------------------------------------------
// Fallback: previous verified single-kernel version (used if ws too small).
// ---------------------------------------------------------------------------
#define QPITCH 72    // elems (144 B): 16B-aligned rows, conflict-free phases

__global__ __launch_bounds__(256, 4)
void cosine_relation_kernel(const float* __restrict__ q,
                            const float* __restrict__ s,
                            float* __restrict__ out)
{
    __shared__ u16 smem[2 * 128 * QPITCH];   // 36864 B: two 128x64 bf16 tiles
    u16* qt = smem;
    u16* st = smem + 128 * QPITCH;

    const int t   = threadIdx.x;
    const int blk = blockIdx.x;           // == (b*25 + i)*25 + j
    const int b   = blk / 625;
    const int rem = blk % 625;
    const int i   = rem / 25;
    const int j   = rem % 25;

    const float* qbase = q + (size_t)(b * 25 + i) * 8192;  // 128x64 fp32
    const float* sbase = s + (size_t)(b * 25 + j) * 8192;

    const int row  = t >> 1;
    const int half = t & 1;
#pragma unroll
    for (int tile = 0; tile < 2; ++tile) {
        const float* gp = (tile == 0 ? qbase : sbase) + row * 64 + half * 32;
        u16*         lp = (tile == 0 ? qt : st) + row * QPITCH + half * 32;
        float4 f[8];
#pragma unroll
        for (int c = 0; c < 8; ++c) f[c] = ((const float4*)gp)[c];
        float ss = 0.f;
#pragma unroll
        for (int c = 0; c < 8; ++c)
            ss += f[c].x*f[c].x + f[c].y*f[c].y + f[c].z*f[c].z + f[c].w*f[c].w;
        ss += __shfl_xor(ss, 1);
        const float r = 1.0f / fmaxf(sqrtf(ss), 1e-12f);
#pragma unroll
        for (int c = 0; c < 4; ++c) {
            uint4v pk;
            pk.x = pack2bf(f[2*c].x * r,   f[2*c].y * r);
            pk.y = pack2bf(f[2*c].z * r,   f[2*c].w * r);
            pk.z = pack2bf(f[2*c+1].x * r, f[2*c+1].y * r);
            pk.w = pack2bf(f[2*c+1].z * r, f[2*c+1].w * r);
            *(uint4v*)(lp + c * 8) = pk;
        }
    }
    __syncthreads();

    const int wave = t >> 6;
    const int lane = t & 63;
    const int quad = lane >> 4;
    const int l15  = lane & 15;
    const int m0   = (wave >> 1) * 64;
    const int n0   = (wave & 1) * 64;

    floatx4 acc[4][4] = {};
#pragma unroll
    for (int ks = 0; ks < 2; ++ks) {
        short8 af[4], bfr[4];
#pragma unroll
        for (int mt = 0; mt < 4; ++mt)
            af[mt] = *(const short8*)(qt + (m0 + mt * 16 + l15) * QPITCH + ks * 32 + quad * 8);
#pragma unroll
        for (int nt = 0; nt < 4; ++nt)
            bfr[nt] = *(const short8*)(st + (n0 + nt * 16 + l15) * QPITCH + ks * 32 + quad * 8);
#pragma unroll
        for (int mt = 0; mt < 4; ++mt)
#pragma unroll
            for (int nt = 0; nt < 4; ++nt)
                acc[mt][nt] = __builtin_amdgcn_mfma_f32_16x16x32_bf16(
                    af[mt], bfr[nt], acc[mt][nt], 0, 0, 0);
    }

    float* obase = out + (size_t)blk * 16384 + n0 + l15;
#pragma unroll
    for (int mt = 0; mt < 4; ++mt) {
#pragma unroll
        for (int r = 0; r < 4; ++r) {
            float* op = obase + (size_t)(m0 + mt * 16 + quad * 4 + r) * 128;
#pragma unroll
            for (int nt = 0; nt < 4; ++nt)
                op[nt * 16] = acc[mt][nt][r];
        }
    }
}

extern "C" void kernel_launch(void* const* d_in, const int* in_sizes, int n_in,
                              void* d_out, int out_size, void* d_ws, size_t ws_size,
                              hipStream_t stream) {
    const float* q = (const float*)d_in[0];
    const float* s = (const float*)d_in[1];
    float* out = (float*)d_out;

    const size_t WS_NEED = (size_t)200 * 16384;   // 3.2 MB bf16 workspace
    if (d_ws != nullptr && ws_size >= WS_NEED) {
        normalize_pack_kernel<<<200, 256, 0, stream>>>(q, s, (u16*)d_ws);
        cosine_gemm_kernel<<<2500, 256, 0, stream>>>((const u16*)d_ws, out);
    } else {
        cosine_relation_kernel<<<2500, 256, 0, stream>>>(q, s, out);
    }
}